// Round 4
// baseline (429.664 us; speedup 1.0000x reference)
//
#include <hip/hip_runtime.h>
#include <hip/hip_bf16.h>

#define N_NODES 100000
#define N_EDGES 250000
#define EMB 32
#define TYPES 16
#define R2 100          // num relations (2*num_rels)
#define STRIPES 24      // stripes per relation for the MFMA kernels

typedef __attribute__((ext_vector_type(8))) short short8;   // 8 bf16 in 4 VGPRs
typedef __attribute__((ext_vector_type(4))) float f32x4;

// fp32 -> bf16 bits, round-to-nearest-even
__device__ __forceinline__ short f2bf(float f) {
    unsigned u = __float_as_uint(f);
    u = (u + 0x7fffu + ((u >> 16) & 1u)) >> 16;
    return (short)u;
}

// ---------------------------------------------------------------------------
// Pass 1 of sort: per-relation histogram (LDS-staged) + float in-degree
__global__ void hist_kernel(const int* __restrict__ etype,
                            const int* __restrict__ edge_dst,
                            int* __restrict__ cnt, float* __restrict__ deg) {
    __shared__ int lh[R2];
    int t = threadIdx.x;
    for (int i = t; i < R2; i += blockDim.x) lh[i] = 0;
    __syncthreads();
    int e = blockIdx.x * blockDim.x + t;
    if (e < N_EDGES) {
        atomicAdd(&lh[etype[e]], 1);
        atomicAdd(&deg[edge_dst[e]], 1.0f);
    }
    __syncthreads();
    for (int i = t; i < R2; i += blockDim.x)
        if (lh[i]) atomicAdd(&cnt[i], lh[i]);
}

// Pass 2: exclusive scan of 100 bins (single block)
__global__ void scan_kernel(const int* __restrict__ cnt,
                            int* __restrict__ off, int* __restrict__ cursor) {
    __shared__ int sd[128];
    int t = threadIdx.x;
    int v = (t < R2) ? cnt[t] : 0;
    sd[t] = v;
    __syncthreads();
    for (int o = 1; o < 128; o <<= 1) {
        int x = (t >= o) ? sd[t - o] : 0;
        __syncthreads();
        sd[t] += x;
        __syncthreads();
    }
    int excl = sd[t] - v;
    if (t < R2) { off[t] = excl; cursor[t] = excl; }
    if (t == R2 - 1) off[R2] = sd[t];
}

// Pass 3: scatter edges into relation-sorted order
__global__ void scatter_kernel(const int* __restrict__ edge_src,
                               const int* __restrict__ edge_dst,
                               const int* __restrict__ etype,
                               int* __restrict__ cursor,
                               int* __restrict__ srcs, int* __restrict__ dsts) {
    int e = blockIdx.x * blockDim.x + threadIdx.x;
    if (e >= N_EDGES) return;
    int r = etype[e];
    int pos = atomicAdd(&cursor[r], 1);
    srcs[pos] = edge_src[e];
    dsts[pos] = edge_dst[e];
}

// ---------------------------------------------------------------------------
// Layer 1: per-relation GEMM tiles [16 edges x 32] = A[16x32] @ W1[r][32x32]
// via 2x mfma_f32_16x16x32_bf16. B-frags persist in registers per stripe.
// A-frag loaded straight from entity (fp32->bf16), layout A[m=lane&15][k=quad*8+j].
__global__ __launch_bounds__(64) void layer1_mfma_kernel(
        const float* __restrict__ entity, const int* __restrict__ src_ids,
        const float* __restrict__ W1, const int* __restrict__ off,
        const int* __restrict__ srcs, const int* __restrict__ dsts,
        float* __restrict__ s1) {
    int bid = blockIdx.x;
    int r = bid % R2;
    int stripe = bid / R2;
    int lo = off[r], hi = off[r + 1];
    int nG = (hi - lo + 15) >> 4;
    if (nG == 0) return;

    int lane = threadIdx.x;
    int n = lane & 15, q = lane >> 4;

    // B-frags for both N-halves: B[k=q*8+j][n]
    const float* Wr = W1 + (size_t)r * (EMB * EMB);
    short8 b0, b1;
#pragma unroll
    for (int j = 0; j < 8; ++j) {
        int k = q * 8 + j;
        b0[j] = f2bf(Wr[k * EMB + n]);
        b1[j] = f2bf(Wr[k * EMB + 16 + n]);
    }

    for (int g = stripe; g < nG; g += STRIPES) {
        int base = lo + g * 16;
        int cl = hi - base; if (cl > 16) cl = 16;          // edges in this tile
        int me = n < cl ? n : cl - 1;                      // clamp A row for tail
        int sid = src_ids[srcs[base + me]];                // h = entity[src_ids[src]]
        const float* hrow = entity + (size_t)sid * EMB + q * 8;
        float4 u = *(const float4*)hrow;
        float4 v = *(const float4*)(hrow + 4);
        short8 a;
        a[0] = f2bf(u.x); a[1] = f2bf(u.y); a[2] = f2bf(u.z); a[3] = f2bf(u.w);
        a[4] = f2bf(v.x); a[5] = f2bf(v.y); a[6] = f2bf(v.z); a[7] = f2bf(v.w);

        f32x4 c0 = {0.f, 0.f, 0.f, 0.f}, c1 = {0.f, 0.f, 0.f, 0.f};
        c0 = __builtin_amdgcn_mfma_f32_16x16x32_bf16(a, b0, c0, 0, 0, 0);
        c1 = __builtin_amdgcn_mfma_f32_16x16x32_bf16(a, b1, c1, 0, 0, 0);

        // C/D layout: col = lane&15 (=n, output), row = q*4+i (edge)
#pragma unroll
        for (int i = 0; i < 4; ++i) {
            int row = q * 4 + i;
            if (row < cl) {
                int d = dsts[base + row];
                atomicAdd(&s1[(size_t)d * EMB + n], c0[i]);
                atomicAdd(&s1[(size_t)d * EMB + 16 + n], c1[i]);
            }
        }
    }
}

// ---------------------------------------------------------------------------
// h1 = relu(s1 / max(deg,1))  in place, float4-vectorized
__global__ void finalize1_kernel(float* __restrict__ s1,
                                 const float* __restrict__ deg) {
    int t = blockIdx.x * blockDim.x + threadIdx.x;   // over N_NODES*8 float4s
    if (t >= N_NODES * (EMB / 4)) return;
    int nnode = t >> 3;
    float inv = 1.0f / fmaxf(deg[nnode], 1.0f);
    float4* p = (float4*)s1 + t;
    float4 v = *p;
    v.x = fmaxf(v.x * inv, 0.f);
    v.y = fmaxf(v.y * inv, 0.f);
    v.z = fmaxf(v.z * inv, 0.f);
    v.w = fmaxf(v.w * inv, 0.f);
    *p = v;
}

// ---------------------------------------------------------------------------
// Layer 2: [16 edges x 16] = A[16x32] @ W2[r][32x16], one MFMA per tile.
__global__ __launch_bounds__(64) void layer2_mfma_kernel(
        const float* __restrict__ h1, const float* __restrict__ W2,
        const int* __restrict__ off, const int* __restrict__ srcs,
        const int* __restrict__ dsts, float* __restrict__ s2) {
    int bid = blockIdx.x;
    int r = bid % R2;
    int stripe = bid / R2;
    int lo = off[r], hi = off[r + 1];
    int nG = (hi - lo + 15) >> 4;
    if (nG == 0) return;

    int lane = threadIdx.x;
    int n = lane & 15, q = lane >> 4;

    const float* Wr = W2 + (size_t)r * (EMB * TYPES);
    short8 b;
#pragma unroll
    for (int j = 0; j < 8; ++j) {
        int k = q * 8 + j;
        b[j] = f2bf(Wr[k * TYPES + n]);
    }

    for (int g = stripe; g < nG; g += STRIPES) {
        int base = lo + g * 16;
        int cl = hi - base; if (cl > 16) cl = 16;
        int me = n < cl ? n : cl - 1;
        int s = srcs[base + me];                           // h1 indexed by node id
        const float* hrow = h1 + (size_t)s * EMB + q * 8;
        float4 u = *(const float4*)hrow;
        float4 v = *(const float4*)(hrow + 4);
        short8 a;
        a[0] = f2bf(u.x); a[1] = f2bf(u.y); a[2] = f2bf(u.z); a[3] = f2bf(u.w);
        a[4] = f2bf(v.x); a[5] = f2bf(v.y); a[6] = f2bf(v.z); a[7] = f2bf(v.w);

        f32x4 c = {0.f, 0.f, 0.f, 0.f};
        c = __builtin_amdgcn_mfma_f32_16x16x32_bf16(a, b, c, 0, 0, 0);

#pragma unroll
        for (int i = 0; i < 4; ++i) {
            int row = q * 4 + i;
            if (row < cl) {
                int d = dsts[base + row];
                atomicAdd(&s2[(size_t)d * TYPES + n], c[i]);
            }
        }
    }
}

// ---------------------------------------------------------------------------
// Head: h2 = s2/max(deg,1);  lam = sigmoid(h2 . lambda_w + lambda_b)
// out = [ y (=h2, twice, [2,N,16]) ; p ([lam,1-lam],[2,N]) ]  fp32
__global__ void head_kernel(const float* __restrict__ s2,
                            const float* __restrict__ deg,
                            const float* __restrict__ lw,
                            const float* __restrict__ lb,
                            float* __restrict__ out) {
    int nn = blockIdx.x * blockDim.x + threadIdx.x;
    if (nn >= N_NODES) return;
    float inv = 1.0f / fmaxf(deg[nn], 1.0f);

    float h[TYPES];
    float dot = 0.f;
#pragma unroll
    for (int j = 0; j < TYPES; ++j) {
        h[j] = s2[nn * TYPES + j] * inv;
        dot += h[j] * lw[j];
    }
    dot += lb[0];
    float lam = 1.0f / (1.0f + expf(-dot));

#pragma unroll
    for (int j = 0; j < TYPES; ++j) {
        float v = h[j];
        out[(size_t)nn * TYPES + j] = v;                              // y[0]
        out[(size_t)N_NODES * TYPES + (size_t)nn * TYPES + j] = v;    // y[1]
    }
    out[(size_t)2 * N_NODES * TYPES + nn] = lam;                      // p[0]
    out[(size_t)2 * N_NODES * TYPES + N_NODES + nn] = 1.0f - lam;     // p[1]
}

// ---------------------------------------------------------------------------
extern "C" void kernel_launch(void* const* d_in, const int* in_sizes, int n_in,
                              void* d_out, int out_size, void* d_ws, size_t ws_size,
                              hipStream_t stream) {
    const float* entity = (const float*)d_in[0];
    const float* W1     = (const float*)d_in[1];
    const float* W2     = (const float*)d_in[2];
    const float* lw     = (const float*)d_in[3];
    const float* lb     = (const float*)d_in[4];
    const int* src_ids  = (const int*)d_in[5];
    const int* edge_src = (const int*)d_in[6];
    const int* edge_dst = (const int*)d_in[7];
    const int* etype    = (const int*)d_in[8];
    float* out = (float*)d_out;

    // ws layout (4B units):
    // s1[3.2M] | s2[1.6M] | deg[100k] | cnt[128] | off[128] | cursor[128] | srcs[250k] | dsts[250k]
    float* s1   = (float*)d_ws;
    float* s2   = s1 + (size_t)N_NODES * EMB;
    float* deg  = s2 + (size_t)N_NODES * TYPES;
    int* cnt    = (int*)(deg + N_NODES);
    int* off    = cnt + 128;
    int* cursor = off + 128;
    int* srcs   = cursor + 128;
    int* dsts   = srcs + N_EDGES;
    // zero s1, s2, deg, cnt (off/cursor written by scan; srcs/dsts fully overwritten)
    size_t zbytes = ((size_t)N_NODES * (EMB + TYPES + 1) + 128) * sizeof(float);
    hipMemsetAsync(d_ws, 0, zbytes, stream);

    const int B = 256;
    hist_kernel<<<(N_EDGES + B - 1) / B, B, 0, stream>>>(etype, edge_dst, cnt, deg);
    scan_kernel<<<1, 128, 0, stream>>>(cnt, off, cursor);
    scatter_kernel<<<(N_EDGES + B - 1) / B, B, 0, stream>>>(
        edge_src, edge_dst, etype, cursor, srcs, dsts);
    layer1_mfma_kernel<<<R2 * STRIPES, 64, 0, stream>>>(
        entity, src_ids, W1, off, srcs, dsts, s1);
    finalize1_kernel<<<(N_NODES * (EMB / 4) + B - 1) / B, B, 0, stream>>>(s1, deg);
    layer2_mfma_kernel<<<R2 * STRIPES, 64, 0, stream>>>(s1, W2, off, srcs, dsts, s2);
    head_kernel<<<(N_NODES + B - 1) / B, B, 0, stream>>>(s2, deg, lw, lb, out);
}

// Round 5
// 172.708 us; speedup vs baseline: 2.4878x; 2.4878x over previous
//
#include <hip/hip_runtime.h>
#include <hip/hip_bf16.h>

#define N_NODES 100000
#define N_EDGES 250000
#define EMB 32
#define TYPES 16
#define R2 100          // num relations (2*num_rels)
#define STRIPES 24      // stripes per relation for the MFMA kernels
#define SB 1024         // sort block size
#define NB ((N_EDGES + SB - 1) / SB)   // 245 sort blocks

typedef __attribute__((ext_vector_type(8))) short short8;   // 8 bf16 in 4 VGPRs
typedef __attribute__((ext_vector_type(4))) float f32x4;

// fp32 -> bf16 bits, round-to-nearest-even
__device__ __forceinline__ short f2bf(float f) {
    unsigned u = __float_as_uint(f);
    u = (u + 0x7fffu + ((u >> 16) & 1u)) >> 16;
    return (short)u;
}

// ---------------------------------------------------------------------------
// Sort pass 1: per-block relation histogram (LDS only) -> counts[b][r]; deg atomics.
__global__ __launch_bounds__(SB) void hist2_kernel(const int* __restrict__ etype,
                                                   const int* __restrict__ edge_dst,
                                                   int* __restrict__ counts,
                                                   float* __restrict__ deg) {
    __shared__ int lh[R2];
    int t = threadIdx.x, b = blockIdx.x;
    if (t < R2) lh[t] = 0;
    __syncthreads();
    int e = b * SB + t;
    if (e < N_EDGES) {
        atomicAdd(&lh[etype[e]], 1);                    // LDS atomic
        atomicAdd(&deg[edge_dst[e]], 1.0f);             // 100k addrs: low contention
    }
    __syncthreads();
    if (t < R2) counts[b * R2 + t] = lh[t];             // write all (zeros included)
}

// Sort pass 2a: per relation, exclusive scan over blocks -> basem[b][r], total[r]
__global__ __launch_bounds__(256) void scanA_kernel(const int* __restrict__ counts,
                                                    int* __restrict__ basem,
                                                    int* __restrict__ total) {
    __shared__ int sd[256];
    int r = blockIdx.x, t = threadIdx.x;
    int v = (t < NB) ? counts[t * R2 + r] : 0;
    sd[t] = v;
    __syncthreads();
    for (int o = 1; o < 256; o <<= 1) {
        int x = (t >= o) ? sd[t - o] : 0;
        __syncthreads();
        sd[t] += x;
        __syncthreads();
    }
    if (t < NB) basem[t * R2 + r] = sd[t] - v;          // exclusive
    if (t == 255) total[r] = sd[t];
}

// Sort pass 2b: exclusive scan of 100 totals -> off[0..R2]
__global__ __launch_bounds__(128) void scanB_kernel(const int* __restrict__ total,
                                                    int* __restrict__ off) {
    __shared__ int sd[128];
    int t = threadIdx.x;
    int v = (t < R2) ? total[t] : 0;
    sd[t] = v;
    __syncthreads();
    for (int o = 1; o < 128; o <<= 1) {
        int x = (t >= o) ? sd[t - o] : 0;
        __syncthreads();
        sd[t] += x;
        __syncthreads();
    }
    if (t < R2) off[t] = sd[t] - v;
    if (t == R2 - 1) off[R2] = sd[t];
}

// Sort pass 3: scatter with LDS-local ranks. No global cursor atomics.
__global__ __launch_bounds__(SB) void scatter2_kernel(const int* __restrict__ edge_src,
                                                      const int* __restrict__ edge_dst,
                                                      const int* __restrict__ etype,
                                                      const int* __restrict__ src_ids,
                                                      const int* __restrict__ basem,
                                                      const int* __restrict__ off,
                                                      int* __restrict__ srcs,
                                                      int* __restrict__ sids,
                                                      int* __restrict__ dsts) {
    __shared__ int lh[R2];
    int t = threadIdx.x, b = blockIdx.x;
    if (t < R2) lh[t] = 0;
    __syncthreads();
    int e = b * SB + t;
    if (e < N_EDGES) {
        int r = etype[e];
        int rank = atomicAdd(&lh[r], 1);                // LDS atomic
        int pos = off[r] + basem[b * R2 + r] + rank;
        int s = edge_src[e];
        srcs[pos] = s;
        sids[pos] = src_ids[s];                         // pre-resolve double indirection
        dsts[pos] = edge_dst[e];
    }
}

// ---------------------------------------------------------------------------
// Layer 1: per-relation tiles [16 edges x 32] = A[16x32] @ W1[r][32x32]
// via 2x mfma_f32_16x16x32_bf16. B-frags persist in registers per stripe.
__global__ __launch_bounds__(64) void layer1_mfma_kernel(
        const float* __restrict__ entity,
        const float* __restrict__ W1, const int* __restrict__ off,
        const int* __restrict__ sids, const int* __restrict__ dsts,
        float* __restrict__ s1) {
    int bid = blockIdx.x;
    int r = bid % R2;
    int stripe = bid / R2;
    int lo = off[r], hi = off[r + 1];
    int nG = (hi - lo + 15) >> 4;
    if (nG == 0) return;

    int lane = threadIdx.x;
    int n = lane & 15, q = lane >> 4;

    // B-frags for both N-halves: B[k=q*8+j][n]
    const float* Wr = W1 + (size_t)r * (EMB * EMB);
    short8 b0, b1;
#pragma unroll
    for (int j = 0; j < 8; ++j) {
        int k = q * 8 + j;
        b0[j] = f2bf(Wr[k * EMB + n]);
        b1[j] = f2bf(Wr[k * EMB + 16 + n]);
    }

    for (int g = stripe; g < nG; g += STRIPES) {
        int base = lo + g * 16;
        int cl = hi - base; if (cl > 16) cl = 16;          // edges in this tile
        int me = n < cl ? n : cl - 1;                      // clamp A row for tail
        int sid = sids[base + me];
        const float* hrow = entity + (size_t)sid * EMB + q * 8;
        float4 u = *(const float4*)hrow;
        float4 v = *(const float4*)(hrow + 4);
        short8 a;
        a[0] = f2bf(u.x); a[1] = f2bf(u.y); a[2] = f2bf(u.z); a[3] = f2bf(u.w);
        a[4] = f2bf(v.x); a[5] = f2bf(v.y); a[6] = f2bf(v.z); a[7] = f2bf(v.w);

        f32x4 c0 = {0.f, 0.f, 0.f, 0.f}, c1 = {0.f, 0.f, 0.f, 0.f};
        c0 = __builtin_amdgcn_mfma_f32_16x16x32_bf16(a, b0, c0, 0, 0, 0);
        c1 = __builtin_amdgcn_mfma_f32_16x16x32_bf16(a, b1, c1, 0, 0, 0);

        // C/D layout: col = lane&15 (=n, output), row = q*4+i (edge)
#pragma unroll
        for (int i = 0; i < 4; ++i) {
            int row = q * 4 + i;
            if (row < cl) {
                int d = dsts[base + row];
                atomicAdd(&s1[(size_t)d * EMB + n], c0[i]);
                atomicAdd(&s1[(size_t)d * EMB + 16 + n], c1[i]);
            }
        }
    }
}

// ---------------------------------------------------------------------------
// h1 = relu(s1 / max(deg,1))  in place, float4-vectorized
__global__ void finalize1_kernel(float* __restrict__ s1,
                                 const float* __restrict__ deg) {
    int t = blockIdx.x * blockDim.x + threadIdx.x;   // over N_NODES*8 float4s
    if (t >= N_NODES * (EMB / 4)) return;
    int nnode = t >> 3;
    float inv = 1.0f / fmaxf(deg[nnode], 1.0f);
    float4* p = (float4*)s1 + t;
    float4 v = *p;
    v.x = fmaxf(v.x * inv, 0.f);
    v.y = fmaxf(v.y * inv, 0.f);
    v.z = fmaxf(v.z * inv, 0.f);
    v.w = fmaxf(v.w * inv, 0.f);
    *p = v;
}

// ---------------------------------------------------------------------------
// Layer 2: [16 edges x 16] = A[16x32] @ W2[r][32x16], one MFMA per tile.
__global__ __launch_bounds__(64) void layer2_mfma_kernel(
        const float* __restrict__ h1, const float* __restrict__ W2,
        const int* __restrict__ off, const int* __restrict__ srcs,
        const int* __restrict__ dsts, float* __restrict__ s2) {
    int bid = blockIdx.x;
    int r = bid % R2;
    int stripe = bid / R2;
    int lo = off[r], hi = off[r + 1];
    int nG = (hi - lo + 15) >> 4;
    if (nG == 0) return;

    int lane = threadIdx.x;
    int n = lane & 15, q = lane >> 4;

    const float* Wr = W2 + (size_t)r * (EMB * TYPES);
    short8 b;
#pragma unroll
    for (int j = 0; j < 8; ++j) {
        int k = q * 8 + j;
        b[j] = f2bf(Wr[k * TYPES + n]);
    }

    for (int g = stripe; g < nG; g += STRIPES) {
        int base = lo + g * 16;
        int cl = hi - base; if (cl > 16) cl = 16;
        int me = n < cl ? n : cl - 1;
        int s = srcs[base + me];                           // h1 indexed by node id
        const float* hrow = h1 + (size_t)s * EMB + q * 8;
        float4 u = *(const float4*)hrow;
        float4 v = *(const float4*)(hrow + 4);
        short8 a;
        a[0] = f2bf(u.x); a[1] = f2bf(u.y); a[2] = f2bf(u.z); a[3] = f2bf(u.w);
        a[4] = f2bf(v.x); a[5] = f2bf(v.y); a[6] = f2bf(v.z); a[7] = f2bf(v.w);

        f32x4 c = {0.f, 0.f, 0.f, 0.f};
        c = __builtin_amdgcn_mfma_f32_16x16x32_bf16(a, b, c, 0, 0, 0);

#pragma unroll
        for (int i = 0; i < 4; ++i) {
            int row = q * 4 + i;
            if (row < cl) {
                int d = dsts[base + row];
                atomicAdd(&s2[(size_t)d * TYPES + n], c[i]);
            }
        }
    }
}

// ---------------------------------------------------------------------------
// Head: h2 = s2/max(deg,1);  lam = sigmoid(h2 . lambda_w + lambda_b)
// out = [ y (=h2, twice, [2,N,16]) ; p ([lam,1-lam],[2,N]) ]  fp32
__global__ void head_kernel(const float* __restrict__ s2,
                            const float* __restrict__ deg,
                            const float* __restrict__ lw,
                            const float* __restrict__ lb,
                            float* __restrict__ out) {
    int nn = blockIdx.x * blockDim.x + threadIdx.x;
    if (nn >= N_NODES) return;
    float inv = 1.0f / fmaxf(deg[nn], 1.0f);

    float h[TYPES];
    float dot = 0.f;
#pragma unroll
    for (int j = 0; j < TYPES; ++j) {
        h[j] = s2[nn * TYPES + j] * inv;
        dot += h[j] * lw[j];
    }
    dot += lb[0];
    float lam = 1.0f / (1.0f + expf(-dot));

#pragma unroll
    for (int j = 0; j < TYPES; ++j) {
        float v = h[j];
        out[(size_t)nn * TYPES + j] = v;                              // y[0]
        out[(size_t)N_NODES * TYPES + (size_t)nn * TYPES + j] = v;    // y[1]
    }
    out[(size_t)2 * N_NODES * TYPES + nn] = lam;                      // p[0]
    out[(size_t)2 * N_NODES * TYPES + N_NODES + nn] = 1.0f - lam;     // p[1]
}

// ---------------------------------------------------------------------------
extern "C" void kernel_launch(void* const* d_in, const int* in_sizes, int n_in,
                              void* d_out, int out_size, void* d_ws, size_t ws_size,
                              hipStream_t stream) {
    const float* entity = (const float*)d_in[0];
    const float* W1     = (const float*)d_in[1];
    const float* W2     = (const float*)d_in[2];
    const float* lw     = (const float*)d_in[3];
    const float* lb     = (const float*)d_in[4];
    const int* src_ids  = (const int*)d_in[5];
    const int* edge_src = (const int*)d_in[6];
    const int* edge_dst = (const int*)d_in[7];
    const int* etype    = (const int*)d_in[8];
    float* out = (float*)d_out;

    // ws layout (4B units):
    // s1[3.2M] | s2[1.6M] | deg[100k] | counts[NB*R2] | basem[NB*R2] | total[128]
    //   | off[128] | srcs[250k] | sids[250k] | dsts[250k]
    float* s1   = (float*)d_ws;
    float* s2   = s1 + (size_t)N_NODES * EMB;
    float* deg  = s2 + (size_t)N_NODES * TYPES;
    int* counts = (int*)(deg + N_NODES);
    int* basem  = counts + NB * R2;
    int* total  = basem + NB * R2;
    int* off    = total + 128;
    int* srcs   = off + 128;
    int* sids   = srcs + N_EDGES;
    int* dsts   = sids + N_EDGES;
    // zero only s1|s2|deg (contiguous); counts/basem/off fully written each call
    size_t zbytes = (size_t)N_NODES * (EMB + TYPES + 1) * sizeof(float);
    hipMemsetAsync(d_ws, 0, zbytes, stream);

    const int B = 256;
    hist2_kernel<<<NB, SB, 0, stream>>>(etype, edge_dst, counts, deg);
    scanA_kernel<<<R2, 256, 0, stream>>>(counts, basem, total);
    scanB_kernel<<<1, 128, 0, stream>>>(total, off);
    scatter2_kernel<<<NB, SB, 0, stream>>>(edge_src, edge_dst, etype, src_ids,
                                           basem, off, srcs, sids, dsts);
    layer1_mfma_kernel<<<R2 * STRIPES, 64, 0, stream>>>(
        entity, W1, off, sids, dsts, s1);
    finalize1_kernel<<<(N_NODES * (EMB / 4) + B - 1) / B, B, 0, stream>>>(s1, deg);
    layer2_mfma_kernel<<<R2 * STRIPES, 64, 0, stream>>>(s1, W2, off, srcs, dsts, s2);
    head_kernel<<<(N_NODES + B - 1) / B, B, 0, stream>>>(s2, deg, lw, lb, out);
}